// Round 1
// baseline (248.155 us; speedup 1.0000x reference)
//
#include <hip/hip_runtime.h>
#include <hip/hip_bf16.h>

// ---------------------------------------------------------------------------
// OrthoInitPhasor: fused bf16-MFMA implementation
//   B=4, S=4096, D=512, CHUNK=64, tokens M=16384
//   GEMM1: x @ [Wk|Wv|Wq]^T       -> KVQ   [16384,1536] bf16
//   GEMM2a: K @ Wkm^T             -> Kmod  [16384,512]  bf16
//   GEMM2b: Q @ Wqm^T             -> Qmod  [16384,512]  bf16
//   phasor+chunk-cumsum+LN        -> normed[16384,512]  bf16
//   GEMM4: normed @ Wo^T + bo + x -> out   [16384,512]  f32
// ---------------------------------------------------------------------------

typedef __attribute__((ext_vector_type(8))) short short8;   // 8 x bf16 (4 VGPR)
typedef __attribute__((ext_vector_type(4))) float f32x4;

#define M_TOK   16384
#define DIM     512
#define SEQ     4096
#define NCHUNK  64

__device__ __forceinline__ void gll16(const void* g, void* l) {
  __builtin_amdgcn_global_load_lds(
      (const __attribute__((address_space(1))) unsigned int*)g,
      (__attribute__((address_space(3))) unsigned int*)l, 16, 0, 0);
}

// --------------------------- f32 -> bf16 convert ---------------------------
__global__ __launch_bounds__(256) void cvt_f32_bf16(
    const float* __restrict__ s, __hip_bfloat16* __restrict__ d, int n4) {
  int i = blockIdx.x * 256 + threadIdx.x;
  if (i >= n4) return;
  float4 v = ((const float4*)s)[i];
  union { __hip_bfloat16 h[4]; uint2 u; } t;
  t.h[0] = __float2bfloat16(v.x);
  t.h[1] = __float2bfloat16(v.y);
  t.h[2] = __float2bfloat16(v.z);
  t.h[3] = __float2bfloat16(v.w);
  ((uint2*)d)[i] = t.u;
}

// ------------------------- pack 6 weights + bias ---------------------------
// Wall layout (bf16): [Wk(512x512) | Wv | Wq | Wkm | Wqm | Wo], each row-major
// bc1 (f32): [bk | bv | bq]  (1536)
__global__ __launch_bounds__(256) void pack_weights(
    const float* __restrict__ wk, const float* __restrict__ wv,
    const float* __restrict__ wq, const float* __restrict__ wkm,
    const float* __restrict__ wqm, const float* __restrict__ wo,
    const float* __restrict__ bk, const float* __restrict__ bv,
    const float* __restrict__ bq,
    __hip_bfloat16* __restrict__ Wall, float* __restrict__ bc1) {
  int t = blockIdx.x * 256 + threadIdx.x;            // 393216 threads
  int m = t >> 16;                                    // which matrix (0..5)
  int r = (t & 65535) * 4;                            // elem offset in matrix
  const float* src;
  switch (m) {
    case 0: src = wk;  break;
    case 1: src = wv;  break;
    case 2: src = wq;  break;
    case 3: src = wkm; break;
    case 4: src = wqm; break;
    default: src = wo; break;
  }
  float4 v = *(const float4*)(src + r);
  union { __hip_bfloat16 h[4]; uint2 u; } o;
  o.h[0] = __float2bfloat16(v.x);
  o.h[1] = __float2bfloat16(v.y);
  o.h[2] = __float2bfloat16(v.z);
  o.h[3] = __float2bfloat16(v.w);
  ((uint2*)(Wall + (size_t)m * 262144))[r >> 2] = o.u;
  if (t < 1536) {
    float b = (t < 512) ? bk[t] : (t < 1024) ? bv[t - 512] : bq[t - 1024];
    bc1[t] = b;
  }
}

// ------------------------------- GEMM (B^T) --------------------------------
// C[m,n] = sum_k A[m,k] * Bt[n,k] + bias[n]   (+ resid[m,n] for EPI==1)
// A: bf16 [M, lda] (K extent = 512), Bt: bf16 [N, 512] row-major
// EPI 0: store bf16 to Cout;  EPI 1: store f32 (acc + bias + resid)
template <int EPI>
__global__ __launch_bounds__(256) void gemm_bt(
    const __hip_bfloat16* __restrict__ A, int lda,
    const __hip_bfloat16* __restrict__ Bt,
    const float* __restrict__ bias,
    void* __restrict__ Cout, int ldc,
    const float* __restrict__ resid) {
  constexpr int K = 512, BK = 32;
  __shared__ __align__(16) __hip_bfloat16 As[128 * BK];
  __shared__ __align__(16) __hip_bfloat16 Bs[128 * BK];

  const int tid  = threadIdx.x;
  const int lane = tid & 63;
  const int w    = tid >> 6;        // wave 0..3
  const int wm   = w >> 1;          // wave row (0..1)
  const int wn   = w & 1;           // wave col (0..1)
  const int m0   = blockIdx.y * 128;
  const int n0   = blockIdx.x * 128;

  // staging: 2 chunks of 1024B per wave per tile; chunk covers 16 rows
  const int rS0    = (w * 2 + 0) * 16 + (lane >> 2);
  const int rS1    = (w * 2 + 1) * 16 + (lane >> 2);
  const int kInRow = (lane & 3) * 8;
  const __hip_bfloat16* gA0 = A + (size_t)(m0 + rS0) * lda + kInRow;
  const __hip_bfloat16* gA1 = A + (size_t)(m0 + rS1) * lda + kInRow;
  const __hip_bfloat16* gB0 = Bt + (size_t)(n0 + rS0) * K + kInRow;
  const __hip_bfloat16* gB1 = Bt + (size_t)(n0 + rS1) * K + kInRow;
  char* ldsA0 = (char*)As + (w * 2 + 0) * 1024;
  char* ldsA1 = (char*)As + (w * 2 + 1) * 1024;
  char* ldsB0 = (char*)Bs + (w * 2 + 0) * 1024;
  char* ldsB1 = (char*)Bs + (w * 2 + 1) * 1024;

  f32x4 acc[4][4] = {};

  const int rfA = lane & 15;        // fragment row within 16-tile
  const int rfK = (lane >> 4) * 8;  // fragment k offset

  for (int kt = 0; kt < K; kt += BK) {
    __syncthreads();
    gll16(gA0 + kt, ldsA0);
    gll16(gA1 + kt, ldsA1);
    gll16(gB0 + kt, ldsB0);
    gll16(gB1 + kt, ldsB1);
    __syncthreads();

    short8 af[4], bf[4];
#pragma unroll
    for (int i = 0; i < 4; i++)
      af[i] = *(const short8*)(As + (wm * 64 + i * 16 + rfA) * BK + rfK);
#pragma unroll
    for (int j = 0; j < 4; j++)
      bf[j] = *(const short8*)(Bs + (wn * 64 + j * 16 + rfA) * BK + rfK);
#pragma unroll
    for (int i = 0; i < 4; i++)
#pragma unroll
      for (int j = 0; j < 4; j++)
        acc[i][j] = __builtin_amdgcn_mfma_f32_16x16x32_bf16(
            af[i], bf[j], acc[i][j], 0, 0, 0);
  }

  // epilogue: C/D layout col = lane&15, row = (lane>>4)*4 + reg
  const int cq = lane >> 4;  // quad
#pragma unroll
  for (int i = 0; i < 4; i++) {
    int row = m0 + wm * 64 + i * 16 + cq * 4;
#pragma unroll
    for (int j = 0; j < 4; j++) {
      int col = n0 + wn * 64 + j * 16 + (lane & 15);
      float bz = bias[col];
#pragma unroll
      for (int r = 0; r < 4; r++) {
        float v = acc[i][j][r] + bz;
        size_t o = (size_t)(row + r) * ldc + col;
        if (EPI == 0) {
          ((__hip_bfloat16*)Cout)[o] = __float2bfloat16(v);
        } else {
          ((float*)Cout)[o] = v + resid[o];
        }
      }
    }
  }
}

// ------------------- phasor + chunk cumsum + LayerNorm ---------------------
// grid: 256 blocks (= B*nC), 512 threads (one per column d)
__global__ __launch_bounds__(512) void phase_cumsum_ln(
    const __hip_bfloat16* __restrict__ KVQ,    // [16384,1536], V at col 512
    const __hip_bfloat16* __restrict__ Kmod,   // [16384,512]
    const __hip_bfloat16* __restrict__ Qmod,   // [16384,512]
    const float* __restrict__ bp,              // [4096,512]
    const float* __restrict__ mod_scale,       // [1]
    const float* __restrict__ ln_g, const float* __restrict__ ln_b,
    __hip_bfloat16* __restrict__ normed) {
  __shared__ __hip_bfloat16 R[64 * 512];       // 64 KB: retrieved (bf16)
  const int d      = threadIdx.x;              // 0..511
  const int blk    = blockIdx.x;               // 0..255
  const int token0 = blk * 64;
  const int sg0    = (blk & (NCHUNK - 1)) * 64;  // base_phases row base
  const float msc  = mod_scale[0];
  const float inv_sqrt_d = 0.044194173824159216f;  // 1/sqrt(512)

  float mr = 0.f, mi = 0.f;
  for (int s = 0; s < 64; ++s) {
    size_t t = (size_t)(token0 + s);
    float v  = __bfloat162float(KVQ[t * 1536 + 512 + d]);
    float km = __bfloat162float(Kmod[t * 512 + d]);
    float qm = __bfloat162float(Qmod[t * 512 + d]);
    float b  = bp[(size_t)(sg0 + s) * 512 + d];
    float kp = b + km * msc;
    float qp = b + qm * msc;
    float sk, ck, sq, cq;
    __sincosf(kp, &sk, &ck);
    __sincosf(qp, &sq, &cq);
    mr += v * ck;
    mi += v * sk;
    R[s * 512 + d] = __float2bfloat16((mr * cq + mi * sq) * inv_sqrt_d);
  }
  __syncthreads();

  const int lane = threadIdx.x & 63;
  const int wv   = threadIdx.x >> 6;  // wave 0..7, owns rows wv*8 .. wv*8+7
  float gj[8], bj[8];
#pragma unroll
  for (int j = 0; j < 8; j++) {
    int col = lane + 64 * j;
    gj[j] = ln_g[col];
    bj[j] = ln_b[col];
  }
  for (int rr = 0; rr < 8; ++rr) {
    int row = wv * 8 + rr;
    float vals[8], sum = 0.f, sq2 = 0.f;
#pragma unroll
    for (int j = 0; j < 8; j++) {
      float x = __bfloat162float(R[row * 512 + lane + 64 * j]);
      vals[j] = x;
      sum += x;
      sq2 += x * x;
    }
#pragma unroll
    for (int off = 32; off; off >>= 1) {
      sum += __shfl_xor(sum, off, 64);
      sq2 += __shfl_xor(sq2, off, 64);
    }
    float mu   = sum * (1.f / 512.f);
    float var  = sq2 * (1.f / 512.f) - mu * mu;
    float rstd = rsqrtf(var + 1e-5f);
    size_t base = (size_t)(token0 + row) * 512;
#pragma unroll
    for (int j = 0; j < 8; j++) {
      int col = lane + 64 * j;
      float nv = (vals[j] - mu) * rstd * gj[j] + bj[j];
      normed[base + col] = __float2bfloat16(nv);
    }
  }
}

// ------------------------------- launcher ----------------------------------
extern "C" void kernel_launch(void* const* d_in, const int* in_sizes, int n_in,
                              void* d_out, int out_size, void* d_ws,
                              size_t ws_size, hipStream_t stream) {
  const float* x    = (const float*)d_in[0];
  const float* bp   = (const float*)d_in[1];
  const float* Wk   = (const float*)d_in[2];
  const float* bk   = (const float*)d_in[3];
  const float* Wv   = (const float*)d_in[4];
  const float* bv   = (const float*)d_in[5];
  const float* Wq   = (const float*)d_in[6];
  const float* bq   = (const float*)d_in[7];
  const float* Wkm  = (const float*)d_in[8];
  const float* bkm  = (const float*)d_in[9];
  const float* Wqm  = (const float*)d_in[10];
  const float* bqm  = (const float*)d_in[11];
  const float* msc  = (const float*)d_in[12];
  const float* lng  = (const float*)d_in[13];
  const float* lnb  = (const float*)d_in[14];
  const float* Wo   = (const float*)d_in[15];
  const float* bo   = (const float*)d_in[16];
  float* out = (float*)d_out;

  char* ws = (char*)d_ws;
  __hip_bfloat16* x_bf = (__hip_bfloat16*)ws;  ws += (size_t)M_TOK * DIM * 2;
  __hip_bfloat16* Wall = (__hip_bfloat16*)ws;  ws += (size_t)6 * 262144 * 2;
  float*          bc1  = (float*)ws;           ws += 1536 * 4;
  __hip_bfloat16* KVQ  = (__hip_bfloat16*)ws;  ws += (size_t)M_TOK * 1536 * 2;
  __hip_bfloat16* Kmod = (__hip_bfloat16*)ws;  ws += (size_t)M_TOK * DIM * 2;
  __hip_bfloat16* Qmod = (__hip_bfloat16*)ws;  ws += (size_t)M_TOK * DIM * 2;
  __hip_bfloat16* nrm  = (__hip_bfloat16*)ws;  ws += (size_t)M_TOK * DIM * 2;

  // 1) convert x to bf16 (8388608 elems / 4 per thread)
  cvt_f32_bf16<<<8192, 256, 0, stream>>>(x, x_bf, 2097152);
  // 2) pack all weights to bf16 + concat bias (393216 threads)
  pack_weights<<<1536, 256, 0, stream>>>(Wk, Wv, Wq, Wkm, Wqm, Wo, bk, bv, bq,
                                         Wall, bc1);
  // 3) KVQ = x @ [Wk|Wv|Wq]^T + [bk|bv|bq]    (M=16384, N=1536)
  gemm_bt<0><<<dim3(12, 128), 256, 0, stream>>>(x_bf, DIM, Wall, bc1, KVQ,
                                                1536, nullptr);
  // 4) Kmod = K @ Wkm^T + bkm ;  Qmod = Q @ Wqm^T + bqm
  gemm_bt<0><<<dim3(4, 128), 256, 0, stream>>>(KVQ + 0, 1536,
                                               Wall + (size_t)3 * 262144, bkm,
                                               Kmod, DIM, nullptr);
  gemm_bt<0><<<dim3(4, 128), 256, 0, stream>>>(KVQ + 1024, 1536,
                                               Wall + (size_t)4 * 262144, bqm,
                                               Qmod, DIM, nullptr);
  // 5) phasor + chunked cumsum + LayerNorm -> normed (bf16)
  phase_cumsum_ln<<<256, 512, 0, stream>>>(KVQ, Kmod, Qmod, bp, msc, lng, lnb,
                                           nrm);
  // 6) out = x + normed @ Wo^T + bo   (f32)
  gemm_bt<1><<<dim3(4, 128), 256, 0, stream>>>(nrm, DIM,
                                               Wall + (size_t)5 * 262144, bo,
                                               out, DIM, x);
}